// Round 4
// baseline (383.805 us; speedup 1.0000x reference)
//
#include <hip/hip_runtime.h>
#include <math.h>

#define D_MODEL 1024
#define D_FF    2048
#define NE      8
#define TOPK    2
#define T_TOKENS 4096
#define TOTAL_ASSIGN (T_TOKENS * TOPK)   // 8192
#define CAP     4096                      // worst-case rows per expert
#define HROWS   (TOTAL_ASSIGN + 128)      // padded assignment rows

typedef __attribute__((ext_vector_type(8))) short bf16x8;
typedef __attribute__((ext_vector_type(4))) float f32x4;

// ---------------- ws layout (bytes) ----------------
#define WS_TOKE   4096                     // int[8192] tok_expert
#define WS_TOKW   (WS_TOKE + 32768)        // float[8192] tok_weight (renormalized top-2)
#define WS_ATOK   (WS_TOKW + 32768)        // int[HROWS] assign_token
#define WS_AWGT   (WS_ATOK + 34816)        // float[HROWS] assign_weight
#define WS_XBF    (WS_AWGT + 34816)        // bf16[4096*1024]      8 MB
#define WS_W1T    (WS_XBF + 8388608)       // bf16[8*2048*1024]   33.5 MB  [e][n][k]
#define WS_W2T    (WS_W1T + 33554432)      // bf16[8*1024*2048]   33.5 MB  [e][n][k]
#define WS_HBF    (WS_W2T + 33554432)      // bf16[HROWS*2048]    34.1 MB
#define WS_PROBS  (WS_HBF + 34078720)      // float[4096*8] softmax probs  128 KB
#define WS_INV    (WS_PROBS + 131072)      // int[8192] token,k -> slot
#define WS_Y      (WS_INV + 32768)         // float[HROWS*1024]  expert outputs 34.1 MB
#define WS_END    (WS_Y + 34078720)        // ~144 MB

__device__ __forceinline__ float gelu_exact(float v) {
    return 0.5f * v * (1.0f + erff(v * 0.70710678118654752440f));
}

__device__ __forceinline__ short f2bf(float f) {
    union { float f; unsigned u; } v; v.f = f;
    unsigned r = v.u + 0x7FFFu + ((v.u >> 16) & 1u);   // RNE
    return (short)(r >> 16);
}

// async 16-B global->LDS (dest = wave-uniform base + lane*16)
__device__ __forceinline__ void async_copy16(void* lds, const void* g) {
    __builtin_amdgcn_global_load_lds(
        (const __attribute__((address_space(1))) unsigned int*)(uintptr_t)g,
        (__attribute__((address_space(3))) unsigned int*)(uintptr_t)lds,
        16, 0, 0);
}

// ---------------- transpose + convert W[e][K][N] -> Wt[e][N][K] bf16 ----------------
__global__ __launch_bounds__(256)
void transpose_convert_kernel(const float* __restrict__ in, short* __restrict__ out,
                              int K, int N) {
    int e = blockIdx.z;
    int k0 = blockIdx.y * 64, n0 = blockIdx.x * 64;
    const float* src = in + (size_t)e * K * N;
    short* dst = out + (size_t)e * N * K;
    __shared__ float tile[64][65];
    int tid = threadIdx.x;
#pragma unroll
    for (int i = 0; i < 4; i++) {
        int lin = i * 256 + tid;
        int kk = lin >> 4;
        int nc = (lin & 15) * 4;
        float4 v = *(const float4*)(src + (size_t)(k0 + kk) * N + n0 + nc);
        tile[kk][nc + 0] = v.x; tile[kk][nc + 1] = v.y;
        tile[kk][nc + 2] = v.z; tile[kk][nc + 3] = v.w;
    }
    __syncthreads();
#pragma unroll
    for (int i = 0; i < 4; i++) {
        int lin = i * 256 + tid;
        int nn = lin >> 4;
        int kc = (lin & 15) * 4;
        short4 o;
        o.x = f2bf(tile[kc + 0][nn]);
        o.y = f2bf(tile[kc + 1][nn]);
        o.z = f2bf(tile[kc + 2][nn]);
        o.w = f2bf(tile[kc + 3][nn]);
        *(short4*)(dst + (size_t)(n0 + nn) * K + k0 + kc) = o;
    }
}

// ---------------- router: one wave per token, no atomics, fused x->bf16 ----------------
__global__ __launch_bounds__(256)
void router_kernel(const float* __restrict__ x,
                   const float* __restrict__ rw,
                   const float* __restrict__ rb,
                   float* __restrict__ probs,
                   int* __restrict__ tok_expert,
                   float* __restrict__ tok_weight,
                   short* __restrict__ xbf) {
    int wid  = threadIdx.x >> 6;
    int lane = threadIdx.x & 63;
    int t = blockIdx.x * 4 + wid;
    if (t >= T_TOKENS) return;

    float acc[NE];
#pragma unroll
    for (int e = 0; e < NE; e++) acc[e] = 0.f;

    const float* xrow = x + (size_t)t * D_MODEL;
    short* xbrow = xbf + (size_t)t * D_MODEL;
#pragma unroll
    for (int i = 0; i < D_MODEL / 64; i++) {
        int d = lane + 64 * i;
        float xv = xrow[d];
        xbrow[d] = f2bf(xv);          // fused conversion
#pragma unroll
        for (int e = 0; e < NE; e++) acc[e] += xv * rw[d * NE + e];
    }
#pragma unroll
    for (int off = 32; off >= 1; off >>= 1) {
#pragma unroll
        for (int e = 0; e < NE; e++) acc[e] += __shfl_down(acc[e], off);
    }

    if (lane == 0) {
        float l[NE], p[NE];
        float m = -1e30f;
#pragma unroll
        for (int e = 0; e < NE; e++) { l[e] = acc[e] + rb[e]; m = fmaxf(m, l[e]); }
        float s = 0.f;
#pragma unroll
        for (int e = 0; e < NE; e++) { p[e] = expf(l[e] - m); s += p[e]; }
        float inv = 1.f / s;
#pragma unroll
        for (int e = 0; e < NE; e++) p[e] *= inv;

        *(float4*)&probs[t * NE]     = make_float4(p[0], p[1], p[2], p[3]);
        *(float4*)&probs[t * NE + 4] = make_float4(p[4], p[5], p[6], p[7]);

        int i1 = 0; float p1 = p[0];
#pragma unroll
        for (int e = 1; e < NE; e++) if (p[e] > p1) { i1 = e; p1 = p[e]; }
        int i2 = -1; float p2 = -1.f;
#pragma unroll
        for (int e = 0; e < NE; e++) if (e != i1 && p[e] > p2) { i2 = e; p2 = p[e]; }

        float den = fmaxf(p1 + p2, 1e-9f);
        tok_expert[2 * t]     = i1;
        tok_expert[2 * t + 1] = i2;
        tok_weight[2 * t]     = p1 / den;
        tok_weight[2 * t + 1] = p2 / den;
    }
}

// ---------------- reduce: counts, offsets, importance, aux (1 block) ----------------
__global__ __launch_bounds__(1024)
void reduce_kernel(const int* __restrict__ tok_expert,
                   const float* __restrict__ probs,
                   int* __restrict__ count,
                   int* __restrict__ offset,
                   int* __restrict__ pos,
                   float* __restrict__ out_aux) {
    __shared__ int   s_cnt[NE];
    __shared__ float s_imp[NE];
    int tid = threadIdx.x;
    if (tid < NE) { s_cnt[tid] = 0; s_imp[tid] = 0.f; }
    __syncthreads();

    int   cnt[NE];
    float imp[NE];
#pragma unroll
    for (int k = 0; k < NE; k++) { cnt[k] = 0; imp[k] = 0.f; }

    for (int j = 0; j < TOTAL_ASSIGN / 1024; j++) {
        int e = tok_expert[tid + 1024 * j];
#pragma unroll
        for (int k = 0; k < NE; k++) cnt[k] += (e == k) ? 1 : 0;
    }
    for (int j = 0; j < T_TOKENS / 1024; j++) {
        const float* pr = probs + (size_t)(tid + 1024 * j) * NE;
        float4 a = *(const float4*)pr;
        float4 b = *(const float4*)(pr + 4);
        imp[0] += a.x; imp[1] += a.y; imp[2] += a.z; imp[3] += a.w;
        imp[4] += b.x; imp[5] += b.y; imp[6] += b.z; imp[7] += b.w;
    }

#pragma unroll
    for (int off = 32; off >= 1; off >>= 1) {
#pragma unroll
        for (int k = 0; k < NE; k++) {
            cnt[k] += __shfl_down(cnt[k], off);
            imp[k] += __shfl_down(imp[k], off);
        }
    }
    if ((tid & 63) == 0) {
#pragma unroll
        for (int k = 0; k < NE; k++) {
            atomicAdd(&s_cnt[k], cnt[k]);
            atomicAdd(&s_imp[k], imp[k]);
        }
    }
    __syncthreads();
    if (tid == 0) {
        int run = 0;
        float a = 0.f;
        for (int e = 0; e < NE; e++) {
            int c = s_cnt[e];
            count[e] = c; offset[e] = run; pos[e] = run; run += c;
            a += (s_imp[e] / (float)T_TOKENS) * ((float)c / (float)TOTAL_ASSIGN);
        }
        out_aux[0] = (float)NE * a;
    }
}

// ---------------- hierarchical scatter: 128 global atomics total ----------------
__global__ __launch_bounds__(256)
void scatter_kernel(const int* __restrict__ tok_expert,
                    const float* __restrict__ tok_weight,
                    int* __restrict__ pos,
                    int* __restrict__ assign_token,
                    float* __restrict__ assign_weight,
                    int* __restrict__ inv_slot) {
    __shared__ int lcnt[NE];
    __shared__ int lbase[NE];
    int tid = threadIdx.x;
    int t = blockIdx.x * 256 + tid;
    if (tid < NE) lcnt[tid] = 0;
    __syncthreads();

    int e[TOPK], lslot[TOPK];
#pragma unroll
    for (int k = 0; k < TOPK; k++) {
        e[k] = tok_expert[2 * t + k];
        lslot[k] = atomicAdd(&lcnt[e[k]], 1);
    }
    __syncthreads();
    if (tid < NE) lbase[tid] = atomicAdd(&pos[tid], lcnt[tid]);
    __syncthreads();
#pragma unroll
    for (int k = 0; k < TOPK; k++) {
        int slot = lbase[e[k]] + lslot[k];
        assign_token[slot]  = t;
        assign_weight[slot] = tok_weight[2 * t + k];
        inv_slot[2 * t + k] = slot;
    }
}

// ---------------- MFMA grouped GEMM, BK=64, XOR-swizzled LDS ----------------
// LDS tile: 128 rows x 64 shorts = 8 chunks(16B)/row; chunk c of row r stored at
// slot r*8 + (c ^ (r&7)). Staging picks source chunk per thread to keep
// global_load_lds's "base + lane*16" dest contiguous; reads XOR on the way out.
// MODE 0: gemm1 (gather x rows, gelu -> hout bf16)
// MODE 1: gemm2, plain stores of y[slot] = acc + bias (fp32)
// MODE 2: gemm2, atomicAdd into out (fallback)
template<int KDIM, int NDIM, int MODE>
__global__ __launch_bounds__(256)
void moe_gemm_kernel(const short* __restrict__ Abase,
                     const short* __restrict__ Wt,
                     const float* __restrict__ bias,
                     const int* __restrict__ count,
                     const int* __restrict__ offset,
                     const int* __restrict__ assign_token,
                     const float* __restrict__ assign_weight,
                     short* __restrict__ hout,
                     float* __restrict__ yout,
                     float* __restrict__ out) {
    int e = blockIdx.z;
    int M = count[e];
    int tm = blockIdx.y;
    if (tm * 128 >= M) return;
    int tn = blockIdx.x;
    int off = offset[e];

    __shared__ __align__(16) short As[128 * 64];   // 16 KB
    __shared__ __align__(16) short Bs[128 * 64];   // 16 KB

    int tid = threadIdx.x;

    // staging: pass p handles slot = p*256 + tid; row = slot>>3 (+32/pass),
    // swizzled chunk cs = slot&7 (invariant), source chunk c = cs ^ (row&7)
    // ((row&7) invariant under +32)
    int r0 = tid >> 3;                 // 0..31
    int c  = (tid & 7) ^ (r0 & 7);     // source chunk, constant over passes
    const short* gA[4];
#pragma unroll
    for (int p = 0; p < 4; p++) {
        int rr = tm * 128 + r0 + 32 * p;
        if (MODE == 0) {
            int tok = (rr < M) ? assign_token[off + rr] : 0;
            gA[p] = Abase + (size_t)tok * KDIM + c * 8;
        } else {
            gA[p] = Abase + (size_t)(off + rr) * KDIM + c * 8;  // padded rows: safe
        }
    }
    const short* gB0 = Wt + ((size_t)e * NDIM + tn * 128 + r0) * KDIM + c * 8;

    int lane = tid & 63;
    int wid  = tid >> 6;
    int rowbase = (wid >> 1) * 64;
    int colbase = (wid & 1) * 64;
    int mrow = lane & 15;
    int quad = lane >> 4;
    int rA = rowbase + mrow;
    int rB = colbase + mrow;

    // read addresses (shorts); frag i adds 16 rows = +1024 shorts, (r&7) invariant
    const short* aRd[2];
    const short* bRd[2];
#pragma unroll
    for (int s0 = 0; s0 < 2; s0++) {
        aRd[s0] = As + (rA * 8 + ((s0 * 4 + quad) ^ (rA & 7))) * 8;
        bRd[s0] = Bs + (rB * 8 + ((s0 * 4 + quad) ^ (rB & 7))) * 8;
    }

    f32x4 acc[4][4];
#pragma unroll
    for (int i = 0; i < 4; i++)
#pragma unroll
        for (int j = 0; j < 4; j++) acc[i][j] = (f32x4){0.f, 0.f, 0.f, 0.f};

    for (int k0 = 0; k0 < KDIM; k0 += 64) {
        __syncthreads();
#pragma unroll
        for (int p = 0; p < 4; p++) {
            async_copy16(As + (p * 256 + tid) * 8, gA[p] + k0);
            async_copy16(Bs + (p * 256 + tid) * 8, gB0 + (size_t)(32 * p) * KDIM + k0);
        }
        __syncthreads();

#pragma unroll
        for (int s0 = 0; s0 < 2; s0++) {
            bf16x8 a[4], b[4];
#pragma unroll
            for (int i = 0; i < 4; i++) a[i] = *(const bf16x8*)(aRd[s0] + i * 1024);
#pragma unroll
            for (int j = 0; j < 4; j++) b[j] = *(const bf16x8*)(bRd[s0] + j * 1024);
#pragma unroll
            for (int i = 0; i < 4; i++)
#pragma unroll
                for (int j = 0; j < 4; j++)
                    acc[i][j] = __builtin_amdgcn_mfma_f32_16x16x32_bf16(a[i], b[j], acc[i][j], 0, 0, 0);
        }
    }

    // epilogue: D row = quad*4 + reg (m), col = lane&15 (n)
    const float* be = bias + (size_t)e * NDIM;
#pragma unroll
    for (int i = 0; i < 4; i++) {
#pragma unroll
        for (int r = 0; r < 4; r++) {
            int row = tm * 128 + rowbase + i * 16 + quad * 4 + r;
            if (row < M) {
                if (MODE == 0) {
                    size_t hrow = (size_t)(off + row) * NDIM;
#pragma unroll
                    for (int j = 0; j < 4; j++) {
                        int col = tn * 128 + colbase + j * 16 + mrow;
                        hout[hrow + col] = f2bf(gelu_exact(acc[i][j][r] + be[col]));
                    }
                } else if (MODE == 1) {
                    float* yp = yout + (size_t)(off + row) * NDIM;
#pragma unroll
                    for (int j = 0; j < 4; j++) {
                        int col = tn * 128 + colbase + j * 16 + mrow;
                        yp[col] = acc[i][j][r] + be[col];
                    }
                } else {
                    int t = assign_token[off + row];
                    float w = assign_weight[off + row];
                    float* op = out + (size_t)t * NDIM;
#pragma unroll
                    for (int j = 0; j < 4; j++) {
                        int col = tn * 128 + colbase + j * 16 + mrow;
                        atomicAdd(&op[col], w * (acc[i][j][r] + be[col]));
                    }
                }
            }
        }
    }
}

// ---------------- combine: out[t] = w1*y[s1] + w2*y[s2] (one block per token) ----------------
__global__ __launch_bounds__(256)
void combine_kernel(const float* __restrict__ y,
                    const int* __restrict__ inv_slot,
                    const float* __restrict__ tok_weight,
                    float* __restrict__ out) {
    int t = blockIdx.x;
    int c = threadIdx.x * 4;
    int s1 = inv_slot[2 * t], s2 = inv_slot[2 * t + 1];
    float w1 = tok_weight[2 * t], w2 = tok_weight[2 * t + 1];
    float4 a = *(const float4*)(y + (size_t)s1 * D_MODEL + c);
    float4 b = *(const float4*)(y + (size_t)s2 * D_MODEL + c);
    float4 o;
    o.x = w1 * a.x + w2 * b.x;
    o.y = w1 * a.y + w2 * b.y;
    o.z = w1 * a.z + w2 * b.z;
    o.w = w1 * a.w + w2 * b.w;
    *(float4*)(out + (size_t)t * D_MODEL + c) = o;
}

extern "C" void kernel_launch(void* const* d_in, const int* in_sizes, int n_in,
                              void* d_out, int out_size, void* d_ws, size_t ws_size,
                              hipStream_t stream) {
    const float* x  = (const float*)d_in[0];
    const float* rw = (const float*)d_in[1];
    const float* rb = (const float*)d_in[2];
    const float* W1 = (const float*)d_in[3];
    const float* b1 = (const float*)d_in[4];
    const float* W2 = (const float*)d_in[5];
    const float* b2 = (const float*)d_in[6];
    float* out = (float*)d_out;

    char* ws = (char*)d_ws;
    int*   count      = (int*)(ws + 0);
    int*   offset     = (int*)(ws + 32);
    int*   pos        = (int*)(ws + 64);
    int*   tok_expert = (int*)(ws + WS_TOKE);
    float* tok_weight = (float*)(ws + WS_TOKW);
    int*   assign_tok = (int*)(ws + WS_ATOK);
    float* assign_wgt = (float*)(ws + WS_AWGT);
    short* xbf        = (short*)(ws + WS_XBF);
    short* W1t        = (short*)(ws + WS_W1T);
    short* W2t        = (short*)(ws + WS_W2T);
    short* hbf        = (short*)(ws + WS_HBF);
    float* probs      = (float*)(ws + WS_PROBS);
    int*   inv_slot   = (int*)(ws + WS_INV);
    float* y          = (float*)(ws + WS_Y);

    bool fits = ws_size >= (size_t)WS_END;

    router_kernel<<<T_TOKENS / 4, 256, 0, stream>>>(x, rw, rb, probs,
                                                    tok_expert, tok_weight, xbf);
    {
        dim3 g(D_FF / 64, D_MODEL / 64, NE);     // W1: K=1024, N=2048
        transpose_convert_kernel<<<g, 256, 0, stream>>>(W1, W1t, D_MODEL, D_FF);
    }
    {
        dim3 g(D_MODEL / 64, D_FF / 64, NE);     // W2: K=2048, N=1024
        transpose_convert_kernel<<<g, 256, 0, stream>>>(W2, W2t, D_FF, D_MODEL);
    }

    reduce_kernel<<<1, 1024, 0, stream>>>(tok_expert, probs, count, offset, pos,
                                          out + (size_t)T_TOKENS * D_MODEL);
    scatter_kernel<<<T_TOKENS / 256, 256, 0, stream>>>(tok_expert, tok_weight, pos,
                                                       assign_tok, assign_wgt, inv_slot);

    {
        dim3 g(D_FF / 128, CAP / 128, NE);       // gemm1: K=1024, N=2048
        moe_gemm_kernel<D_MODEL, D_FF, 0><<<g, 256, 0, stream>>>(
            xbf, W1t, b1, count, offset, assign_tok, assign_wgt, hbf, nullptr, nullptr);
    }

    if (fits) {
        dim3 g(D_MODEL / 128, CAP / 128, NE);    // gemm2: K=2048, N=1024
        moe_gemm_kernel<D_FF, D_MODEL, 1><<<g, 256, 0, stream>>>(
            hbf, W2t, b2, count, offset, assign_tok, assign_wgt, nullptr, y, nullptr);
        combine_kernel<<<T_TOKENS, 256, 0, stream>>>(y, inv_slot, tok_weight, out);
    } else {
        hipMemsetAsync(d_out, 0, (size_t)T_TOKENS * D_MODEL * sizeof(float), stream);
        dim3 g(D_MODEL / 128, CAP / 128, NE);
        moe_gemm_kernel<D_FF, D_MODEL, 2><<<g, 256, 0, stream>>>(
            hbf, W2t, b2, count, offset, assign_tok, assign_wgt, nullptr, nullptr, out);
    }
}

// Round 5
// 357.773 us; speedup vs baseline: 1.0728x; 1.0728x over previous
//
#include <hip/hip_runtime.h>
#include <math.h>

#define D_MODEL 1024
#define D_FF    2048
#define NE      8
#define TOPK    2
#define T_TOKENS 4096
#define TOTAL_ASSIGN (T_TOKENS * TOPK)   // 8192
#define CAP     4096                      // worst-case rows per expert
#define HROWS   (TOTAL_ASSIGN + 128)      // padded assignment rows

typedef __attribute__((ext_vector_type(8))) short bf16x8;
typedef __attribute__((ext_vector_type(4))) float f32x4;

// ---------------- ws layout (bytes) ----------------
#define WS_TOKE   4096                     // int[8192] tok_expert
#define WS_TOKW   (WS_TOKE + 32768)        // float[8192] tok_weight (renormalized top-2)
#define WS_ATOK   (WS_TOKW + 32768)        // int[HROWS] assign_token
#define WS_AWGT   (WS_ATOK + 34816)        // float[HROWS] assign_weight
#define WS_XBF    (WS_AWGT + 34816)        // bf16[4096*1024]      8 MB
#define WS_W1T    (WS_XBF + 8388608)       // bf16[8*2048*1024]   33.5 MB  [e][n][k]
#define WS_W2T    (WS_W1T + 33554432)      // bf16[8*1024*2048]   33.5 MB  [e][n][k]
#define WS_HBF    (WS_W2T + 33554432)      // bf16[HROWS*2048]    34.1 MB
#define WS_PROBS  (WS_HBF + 34078720)      // float[4096*8] softmax probs  128 KB
#define WS_INV    (WS_PROBS + 131072)      // int[8192] token,k -> slot
#define WS_Y      (WS_INV + 32768)         // float[HROWS*1024]  expert outputs 34.1 MB
#define WS_END    (WS_Y + 34078720)        // ~144 MB

__device__ __forceinline__ float gelu_exact(float v) {
    return 0.5f * v * (1.0f + erff(v * 0.70710678118654752440f));
}

__device__ __forceinline__ short f2bf(float f) {
    union { float f; unsigned u; } v; v.f = f;
    unsigned r = v.u + 0x7FFFu + ((v.u >> 16) & 1u);   // RNE
    return (short)(r >> 16);
}

// async 16-B global->LDS (dest = wave-uniform base + lane*16)
__device__ __forceinline__ void async_copy16(void* lds, const void* g) {
    __builtin_amdgcn_global_load_lds(
        (const __attribute__((address_space(1))) unsigned int*)(uintptr_t)g,
        (__attribute__((address_space(3))) unsigned int*)(uintptr_t)lds,
        16, 0, 0);
}

// ---------------- transpose + convert W[e][K][N] -> Wt[e][N][K] bf16 ----------------
__global__ __launch_bounds__(256)
void transpose_convert_kernel(const float* __restrict__ in, short* __restrict__ out,
                              int K, int N) {
    int e = blockIdx.z;
    int k0 = blockIdx.y * 64, n0 = blockIdx.x * 64;
    const float* src = in + (size_t)e * K * N;
    short* dst = out + (size_t)e * N * K;
    __shared__ float tile[64][65];
    int tid = threadIdx.x;
#pragma unroll
    for (int i = 0; i < 4; i++) {
        int lin = i * 256 + tid;
        int kk = lin >> 4;
        int nc = (lin & 15) * 4;
        float4 v = *(const float4*)(src + (size_t)(k0 + kk) * N + n0 + nc);
        tile[kk][nc + 0] = v.x; tile[kk][nc + 1] = v.y;
        tile[kk][nc + 2] = v.z; tile[kk][nc + 3] = v.w;
    }
    __syncthreads();
#pragma unroll
    for (int i = 0; i < 4; i++) {
        int lin = i * 256 + tid;
        int nn = lin >> 4;
        int kc = (lin & 15) * 4;
        short4 o;
        o.x = f2bf(tile[kc + 0][nn]);
        o.y = f2bf(tile[kc + 1][nn]);
        o.z = f2bf(tile[kc + 2][nn]);
        o.w = f2bf(tile[kc + 3][nn]);
        *(short4*)(dst + (size_t)(n0 + nn) * K + k0 + kc) = o;
    }
}

// ---------------- router: one wave per token, no atomics, fused x->bf16 ----------------
__global__ __launch_bounds__(256)
void router_kernel(const float* __restrict__ x,
                   const float* __restrict__ rw,
                   const float* __restrict__ rb,
                   float* __restrict__ probs,
                   int* __restrict__ tok_expert,
                   float* __restrict__ tok_weight,
                   short* __restrict__ xbf) {
    int wid  = threadIdx.x >> 6;
    int lane = threadIdx.x & 63;
    int t = blockIdx.x * 4 + wid;
    if (t >= T_TOKENS) return;

    float acc[NE];
#pragma unroll
    for (int e = 0; e < NE; e++) acc[e] = 0.f;

    const float* xrow = x + (size_t)t * D_MODEL;
    short* xbrow = xbf + (size_t)t * D_MODEL;
#pragma unroll
    for (int i = 0; i < D_MODEL / 64; i++) {
        int d = lane + 64 * i;
        float xv = xrow[d];
        xbrow[d] = f2bf(xv);          // fused conversion
#pragma unroll
        for (int e = 0; e < NE; e++) acc[e] += xv * rw[d * NE + e];
    }
#pragma unroll
    for (int off = 32; off >= 1; off >>= 1) {
#pragma unroll
        for (int e = 0; e < NE; e++) acc[e] += __shfl_down(acc[e], off);
    }

    if (lane == 0) {
        float l[NE], p[NE];
        float m = -1e30f;
#pragma unroll
        for (int e = 0; e < NE; e++) { l[e] = acc[e] + rb[e]; m = fmaxf(m, l[e]); }
        float s = 0.f;
#pragma unroll
        for (int e = 0; e < NE; e++) { p[e] = expf(l[e] - m); s += p[e]; }
        float inv = 1.f / s;
#pragma unroll
        for (int e = 0; e < NE; e++) p[e] *= inv;

        *(float4*)&probs[t * NE]     = make_float4(p[0], p[1], p[2], p[3]);
        *(float4*)&probs[t * NE + 4] = make_float4(p[4], p[5], p[6], p[7]);

        int i1 = 0; float p1 = p[0];
#pragma unroll
        for (int e = 1; e < NE; e++) if (p[e] > p1) { i1 = e; p1 = p[e]; }
        int i2 = -1; float p2 = -1.f;
#pragma unroll
        for (int e = 0; e < NE; e++) if (e != i1 && p[e] > p2) { i2 = e; p2 = p[e]; }

        float den = fmaxf(p1 + p2, 1e-9f);
        tok_expert[2 * t]     = i1;
        tok_expert[2 * t + 1] = i2;
        tok_weight[2 * t]     = p1 / den;
        tok_weight[2 * t + 1] = p2 / den;
    }
}

// ---------------- reduce: counts, offsets, importance, aux (1 block) ----------------
__global__ __launch_bounds__(1024)
void reduce_kernel(const int* __restrict__ tok_expert,
                   const float* __restrict__ probs,
                   int* __restrict__ count,
                   int* __restrict__ offset,
                   int* __restrict__ pos,
                   float* __restrict__ out_aux) {
    __shared__ int   s_cnt[NE];
    __shared__ float s_imp[NE];
    int tid = threadIdx.x;
    if (tid < NE) { s_cnt[tid] = 0; s_imp[tid] = 0.f; }
    __syncthreads();

    int   cnt[NE];
    float imp[NE];
#pragma unroll
    for (int k = 0; k < NE; k++) { cnt[k] = 0; imp[k] = 0.f; }

    for (int j = 0; j < TOTAL_ASSIGN / 1024; j++) {
        int e = tok_expert[tid + 1024 * j];
#pragma unroll
        for (int k = 0; k < NE; k++) cnt[k] += (e == k) ? 1 : 0;
    }
    for (int j = 0; j < T_TOKENS / 1024; j++) {
        const float* pr = probs + (size_t)(tid + 1024 * j) * NE;
        float4 a = *(const float4*)pr;
        float4 b = *(const float4*)(pr + 4);
        imp[0] += a.x; imp[1] += a.y; imp[2] += a.z; imp[3] += a.w;
        imp[4] += b.x; imp[5] += b.y; imp[6] += b.z; imp[7] += b.w;
    }

#pragma unroll
    for (int off = 32; off >= 1; off >>= 1) {
#pragma unroll
        for (int k = 0; k < NE; k++) {
            cnt[k] += __shfl_down(cnt[k], off);
            imp[k] += __shfl_down(imp[k], off);
        }
    }
    if ((tid & 63) == 0) {
#pragma unroll
        for (int k = 0; k < NE; k++) {
            atomicAdd(&s_cnt[k], cnt[k]);
            atomicAdd(&s_imp[k], imp[k]);
        }
    }
    __syncthreads();
    if (tid == 0) {
        int run = 0;
        float a = 0.f;
        for (int e = 0; e < NE; e++) {
            int c = s_cnt[e];
            count[e] = c; offset[e] = run; pos[e] = run; run += c;
            a += (s_imp[e] / (float)T_TOKENS) * ((float)c / (float)TOTAL_ASSIGN);
        }
        out_aux[0] = (float)NE * a;
    }
}

// ---------------- hierarchical scatter: 128 global atomics total ----------------
__global__ __launch_bounds__(256)
void scatter_kernel(const int* __restrict__ tok_expert,
                    const float* __restrict__ tok_weight,
                    int* __restrict__ pos,
                    int* __restrict__ assign_token,
                    float* __restrict__ assign_weight,
                    int* __restrict__ inv_slot) {
    __shared__ int lcnt[NE];
    __shared__ int lbase[NE];
    int tid = threadIdx.x;
    int t = blockIdx.x * 256 + tid;
    if (tid < NE) lcnt[tid] = 0;
    __syncthreads();

    int e[TOPK], lslot[TOPK];
#pragma unroll
    for (int k = 0; k < TOPK; k++) {
        e[k] = tok_expert[2 * t + k];
        lslot[k] = atomicAdd(&lcnt[e[k]], 1);
    }
    __syncthreads();
    if (tid < NE) lbase[tid] = atomicAdd(&pos[tid], lcnt[tid]);
    __syncthreads();
#pragma unroll
    for (int k = 0; k < TOPK; k++) {
        int slot = lbase[e[k]] + lslot[k];
        assign_token[slot]  = t;
        assign_weight[slot] = tok_weight[2 * t + k];
        inv_slot[2 * t + k] = slot;
    }
}

// ---------------- MFMA grouped GEMM, BK=32, 2-way-free XOR swizzle ----------------
// LDS K-tile: 128 rows x 32 shorts = 4 chunks(16B)/row; chunk c of row r stored
// at slot c ^ (r&3)  ->  every ds_read_b128 is exactly 2-way (free, m136).
// Epilogue: acc frags -> fp32 LDS scratch [col][row^(4*(col&7))] (b128 writes),
// read back row-major, bias(+gelu), coalesced vector stores.
// MODE 0: gemm1 (gather x rows, gelu -> hout bf16)
// MODE 1: gemm2, plain stores of y[slot] = acc + bias (fp32)
// MODE 2: gemm2, atomicAdd into out (fallback)
template<int KDIM, int NDIM, int MODE>
__global__ __launch_bounds__(256)
void moe_gemm_kernel(const short* __restrict__ Abase,
                     const short* __restrict__ Wt,
                     const float* __restrict__ bias,
                     const int* __restrict__ count,
                     const int* __restrict__ offset,
                     const int* __restrict__ assign_token,
                     const float* __restrict__ assign_weight,
                     short* __restrict__ hout,
                     float* __restrict__ yout,
                     float* __restrict__ out) {
    int e = blockIdx.z;
    int M = count[e];
    int tm = blockIdx.y;
    if (tm * 128 >= M) return;
    int tn = blockIdx.x;
    int off = offset[e];

    __shared__ __align__(16) char smem[32768];
    short* As = (short*)smem;              // 8 KB
    short* Bs = (short*)(smem + 8192);     // 8 KB
    float* sc = (float*)smem;              // 32 KB epilogue scratch [col][64]

    int tid = threadIdx.x;
    int r0 = tid >> 2;                     // 0..63
    int cs = (tid & 3) ^ (r0 & 3);         // source chunk, (r&3) invariant under +64

    const short* gA[2];
#pragma unroll
    for (int p = 0; p < 2; p++) {
        int rr = tm * 128 + r0 + 64 * p;
        if (MODE == 0) {
            int tok = (rr < M) ? assign_token[off + rr] : 0;
            gA[p] = Abase + (size_t)tok * KDIM + cs * 8;
        } else {
            gA[p] = Abase + (size_t)(off + rr) * KDIM + cs * 8;  // padded rows: safe
        }
    }
    const short* gB0 = Wt + ((size_t)e * NDIM + tn * 128 + r0) * KDIM + cs * 8;

    int lane = tid & 63;
    int wid  = tid >> 6;
    int rowbase = (wid >> 1) * 64;
    int colbase = (wid & 1) * 64;
    int mrow = lane & 15;
    int quad = lane >> 4;
    int rA = rowbase + mrow;
    int rB = colbase + mrow;
    const short* aRd = As + (rA * 4 + (quad ^ (rA & 3))) * 8;   // frag i: +i*512
    const short* bRd = Bs + (rB * 4 + (quad ^ (rB & 3))) * 8;

    f32x4 acc[4][4];
#pragma unroll
    for (int i = 0; i < 4; i++)
#pragma unroll
        for (int j = 0; j < 4; j++) acc[i][j] = (f32x4){0.f, 0.f, 0.f, 0.f};

    for (int k0 = 0; k0 < KDIM; k0 += 32) {
        __syncthreads();
        async_copy16(As + tid * 8,         gA[0] + k0);
        async_copy16(As + (256 + tid) * 8, gA[1] + k0);
        async_copy16(Bs + tid * 8,         gB0 + k0);
        async_copy16(Bs + (256 + tid) * 8, gB0 + (size_t)64 * KDIM + k0);
        __syncthreads();

        bf16x8 a[4], b[4];
#pragma unroll
        for (int i = 0; i < 4; i++) a[i] = *(const bf16x8*)(aRd + i * 512);
#pragma unroll
        for (int j = 0; j < 4; j++) b[j] = *(const bf16x8*)(bRd + j * 512);
#pragma unroll
        for (int i = 0; i < 4; i++)
#pragma unroll
            for (int j = 0; j < 4; j++)
                acc[i][j] = __builtin_amdgcn_mfma_f32_16x16x32_bf16(a[i], b[j], acc[i][j], 0, 0, 0);
    }

    const float* be2 = bias + (size_t)e * NDIM + tn * 128;

    if (MODE == 2) {
        // legacy atomic epilogue (fallback only)
#pragma unroll
        for (int i = 0; i < 4; i++) {
#pragma unroll
            for (int r = 0; r < 4; r++) {
                int row = tm * 128 + rowbase + i * 16 + quad * 4 + r;
                if (row < M) {
                    int t = assign_token[off + row];
                    float w = assign_weight[off + row];
                    float* op = out + (size_t)t * NDIM + tn * 128;
#pragma unroll
                    for (int j = 0; j < 4; j++) {
                        int col = colbase + j * 16 + mrow;
                        atomicAdd(&op[col], w * (acc[i][j][r] + be2[col]));
                    }
                }
            }
        }
        return;
    }

    // vectorized epilogue: 2 half-tiles of 64 rows through 32 KB scratch
    int c4 = (tid & 31) * 4;          // read-phase column base
    int rb = tid >> 5;                // read-phase row base (0..7)
    float4 bv = *(const float4*)(be2 + c4);
    float bias4[4] = {bv.x, bv.y, bv.z, bv.w};

    for (int h = 0; h < 2; h++) {
        __syncthreads();              // protect As/Bs (h=0) or prior reads (h=1)
        if ((wid >> 1) == h) {
#pragma unroll
            for (int i = 0; i < 4; i++)
#pragma unroll
                for (int j = 0; j < 4; j++) {
                    int col = colbase + j * 16 + mrow;
                    int row = i * 16 + quad * 4;          // local 0..63, 4-aligned
                    *(f32x4*)(sc + col * 64 + (row ^ (4 * (col & 7)))) = acc[i][j];
                }
        }
        __syncthreads();
#pragma unroll
        for (int g = 0; g < 8; g++) {
            int lrow = rb + 8 * g;                        // local row 0..63
            int grow = tm * 128 + h * 64 + lrow;
            if (grow < M) {
                float v[4];
#pragma unroll
                for (int m = 0; m < 4; m++) {
                    int col = c4 + m;
                    v[m] = sc[col * 64 + (lrow ^ (4 * (col & 7)))] + bias4[m];
                }
                if (MODE == 0) {
                    short4 o;
                    o.x = f2bf(gelu_exact(v[0]));
                    o.y = f2bf(gelu_exact(v[1]));
                    o.z = f2bf(gelu_exact(v[2]));
                    o.w = f2bf(gelu_exact(v[3]));
                    *(short4*)(hout + (size_t)(off + grow) * NDIM + tn * 128 + c4) = o;
                } else {
                    *(float4*)(yout + (size_t)(off + grow) * NDIM + tn * 128 + c4) =
                        make_float4(v[0], v[1], v[2], v[3]);
                }
            }
        }
    }
}

// ---------------- combine: out[t] = w1*y[s1] + w2*y[s2] (one block per token) ----------------
__global__ __launch_bounds__(256)
void combine_kernel(const float* __restrict__ y,
                    const int* __restrict__ inv_slot,
                    const float* __restrict__ tok_weight,
                    float* __restrict__ out) {
    int t = blockIdx.x;
    int c = threadIdx.x * 4;
    int s1 = inv_slot[2 * t], s2 = inv_slot[2 * t + 1];
    float w1 = tok_weight[2 * t], w2 = tok_weight[2 * t + 1];
    float4 a = *(const float4*)(y + (size_t)s1 * D_MODEL + c);
    float4 b = *(const float4*)(y + (size_t)s2 * D_MODEL + c);
    float4 o;
    o.x = w1 * a.x + w2 * b.x;
    o.y = w1 * a.y + w2 * b.y;
    o.z = w1 * a.z + w2 * b.z;
    o.w = w1 * a.w + w2 * b.w;
    *(float4*)(out + (size_t)t * D_MODEL + c) = o;
}

extern "C" void kernel_launch(void* const* d_in, const int* in_sizes, int n_in,
                              void* d_out, int out_size, void* d_ws, size_t ws_size,
                              hipStream_t stream) {
    const float* x  = (const float*)d_in[0];
    const float* rw = (const float*)d_in[1];
    const float* rb = (const float*)d_in[2];
    const float* W1 = (const float*)d_in[3];
    const float* b1 = (const float*)d_in[4];
    const float* W2 = (const float*)d_in[5];
    const float* b2 = (const float*)d_in[6];
    float* out = (float*)d_out;

    char* ws = (char*)d_ws;
    int*   count      = (int*)(ws + 0);
    int*   offset     = (int*)(ws + 32);
    int*   pos        = (int*)(ws + 64);
    int*   tok_expert = (int*)(ws + WS_TOKE);
    float* tok_weight = (float*)(ws + WS_TOKW);
    int*   assign_tok = (int*)(ws + WS_ATOK);
    float* assign_wgt = (float*)(ws + WS_AWGT);
    short* xbf        = (short*)(ws + WS_XBF);
    short* W1t        = (short*)(ws + WS_W1T);
    short* W2t        = (short*)(ws + WS_W2T);
    short* hbf        = (short*)(ws + WS_HBF);
    float* probs      = (float*)(ws + WS_PROBS);
    int*   inv_slot   = (int*)(ws + WS_INV);
    float* y          = (float*)(ws + WS_Y);

    bool fits = ws_size >= (size_t)WS_END;

    router_kernel<<<T_TOKENS / 4, 256, 0, stream>>>(x, rw, rb, probs,
                                                    tok_expert, tok_weight, xbf);
    {
        dim3 g(D_FF / 64, D_MODEL / 64, NE);     // W1: K=1024, N=2048
        transpose_convert_kernel<<<g, 256, 0, stream>>>(W1, W1t, D_MODEL, D_FF);
    }
    {
        dim3 g(D_MODEL / 64, D_FF / 64, NE);     // W2: K=2048, N=1024
        transpose_convert_kernel<<<g, 256, 0, stream>>>(W2, W2t, D_FF, D_MODEL);
    }

    reduce_kernel<<<1, 1024, 0, stream>>>(tok_expert, probs, count, offset, pos,
                                          out + (size_t)T_TOKENS * D_MODEL);
    scatter_kernel<<<T_TOKENS / 256, 256, 0, stream>>>(tok_expert, tok_weight, pos,
                                                       assign_tok, assign_wgt, inv_slot);

    {
        dim3 g(D_FF / 128, CAP / 128, NE);       // gemm1: K=1024, N=2048
        moe_gemm_kernel<D_MODEL, D_FF, 0><<<g, 256, 0, stream>>>(
            xbf, W1t, b1, count, offset, assign_tok, assign_wgt, hbf, nullptr, nullptr);
    }

    if (fits) {
        dim3 g(D_MODEL / 128, CAP / 128, NE);    // gemm2: K=2048, N=1024
        moe_gemm_kernel<D_FF, D_MODEL, 1><<<g, 256, 0, stream>>>(
            hbf, W2t, b2, count, offset, assign_tok, assign_wgt, nullptr, y, nullptr);
        combine_kernel<<<T_TOKENS, 256, 0, stream>>>(y, inv_slot, tok_weight, out);
    } else {
        hipMemsetAsync(d_out, 0, (size_t)T_TOKENS * D_MODEL * sizeof(float), stream);
        dim3 g(D_MODEL / 128, CAP / 128, NE);
        moe_gemm_kernel<D_FF, D_MODEL, 2><<<g, 256, 0, stream>>>(
            hbf, W2t, b2, count, offset, assign_tok, assign_wgt, nullptr, nullptr, out);
    }
}